// Round 6
// baseline (256.585 us; speedup 1.0000x reference)
//
#include <hip/hip_runtime.h>

#define F 128
#define GRAPHS 64
#define GN_EPS 1e-5f
#define PB 256          // partition blocks / histogram chunks

typedef short short8 __attribute__((ext_vector_type(8)));
typedef float f32x4 __attribute__((ext_vector_type(4)));

__device__ __forceinline__ unsigned short f2b(float f) {      // fp32 -> bf16 RNE
    unsigned u = __float_as_uint(f);
    unsigned r = (u + 0x7fffu + ((u >> 16) & 1u)) >> 16;
    return (unsigned short)r;
}
__device__ __forceinline__ float b2f(unsigned short h) {      // bf16 -> fp32
    return __uint_as_float(((unsigned)h) << 16);
}

struct MArgs {
    const float* y; const int* ei; const float* ew; const int* batch;
    const float* tw; const float* tb; const float* gnw; const float* gnb; const float* gms;
    float* res;
    float* S1; float* S2; int* gstart; float* dinv; int* offs; int* hist_t; int* bbase;
    uint2* part; unsigned* csr; unsigned short* Wf; unsigned short* hcat; unsigned short* outb;
    int N, E, NB, chunk, fb, gb;
    size_t NF;
};

// ---------------- k_prep: hist | f2b | wcvt | gstart | zero S1/S2 -----------------
__global__ __launch_bounds__(256) void k_prep(MArgs a) {
    __shared__ int hist[256];
    const int t0 = 256;            // hist tasks
    const int t1 = t0 + a.fb;      // f2b tasks
    const int t2 = t1 + 256;       // wcvt tasks (65536 elems)
    const int t3 = t2 + a.gb;      // gstart tasks
    int tid = threadIdx.x;
    int task = blockIdx.x;
    if (task < t0) {                               // ---- per-chunk dst-bucket histogram
        hist[tid] = 0;
        __syncthreads();
        int e0 = task * a.chunk, e1 = min(e0 + a.chunk, a.E);
        for (int e = e0 + tid; e < e1; e += 256)
            atomicAdd(&hist[a.ei[a.E + e] >> 8], 1);
        __syncthreads();
        for (int k = tid; k < a.NB; k += 256)
            a.hist_t[k * PB + task] = hist[k];
    } else if (task < t1) {                        // ---- y fp32 -> bf16 (hs0)
        int i = (task - t0) * 256 + tid;
        if (i < a.N * 32) {
            float4 v = ((const float4*)a.y)[i];
            ((ushort4*)a.hcat)[i] = make_ushort4(f2b(v.x), f2b(v.y), f2b(v.z), f2b(v.w));
        }
    } else if (task < t2) {                        // ---- weight convert/permute
        int i = (task - t1) * 256 + tid;
        int seg = i >> 14;
        int r = i & 16383;
        int kb = r >> 12;
        int wcc = (r >> 11) & 1;
        int ntt = (r >> 9) & 3;
        int lane = (r >> 3) & 63;
        int j = i & 7;
        int k = kb * 32 + (lane >> 4) * 8 + j;
        int nn = wcc * 64 + ntt * 16 + (lane & 15);
        a.Wf[i] = f2b(a.tw[seg * 16384 + k * 128 + nn]);
    } else if (task < t3) {                        // ---- gstart (batch is sorted)
        int i = (task - t2) * 256 + tid;
        if (i < a.N) {
            int bb = a.batch[i];
            if (i == 0) {
                for (int g = 0; g <= bb; ++g) a.gstart[g] = 0;
            } else {
                int bp = a.batch[i - 1];
                for (int g = bp + 1; g <= bb; ++g) a.gstart[g] = i;
            }
            if (i == a.N - 1) {
                for (int g = bb + 1; g <= GRAPHS; ++g) a.gstart[g] = a.N;
            }
        }
    } else {                                       // ---- zero S1/S2 (contiguous)
        int z = task - t3;
        float* dst = a.S1 + z * 2048;
        for (int i2 = tid; i2 < 2048; i2 += 256) dst[i2] = 0.f;
    }
}

// --------- k_part: partition edges into dst-buckets; scan folded in ---------------
__global__ __launch_bounds__(256) void k_part(MArgs a) {
    __shared__ int cur[256];
    __shared__ int rs[256];
    int t = threadIdx.x;
    int k = blockIdx.x;
    int total = 0, pref = 0;
    if (t < a.NB) {
        const int4* row = (const int4*)(a.hist_t + t * PB);
        for (int q = 0; q < PB / 4; ++q) {
            int4 v = row[q];
            int c4 = q * 4;
            total += v.x + v.y + v.z + v.w;
            if (c4 + 4 <= k) pref += v.x + v.y + v.z + v.w;
            else {
                if (c4 + 0 < k) pref += v.x;
                if (c4 + 1 < k) pref += v.y;
                if (c4 + 2 < k) pref += v.z;
                if (c4 + 3 < k) pref += v.w;
            }
        }
    }
    rs[t] = (t < a.NB) ? total : 0;
    __syncthreads();
    for (int off = 1; off < 256; off <<= 1) {       // inclusive scan of row sums
        int x = (t >= off) ? rs[t - off] : 0;
        __syncthreads();
        rs[t] += x;
        __syncthreads();
    }
    int rowStart = (t > 0) ? rs[t - 1] : 0;         // exclusive bucket base
    cur[t] = rowStart + pref;
    if (k == 0 && t <= a.NB) a.bbase[t] = rowStart; // bbase[NB] == E
    __syncthreads();
    int e0 = k * a.chunk, e1 = min(e0 + a.chunk, a.E);
    for (int e = e0 + t; e < e1; e += 256) {
        int dst = a.ei[a.E + e];
        int src = a.ei[e];
        float w = a.ew[e];
        int slot = atomicAdd(&cur[dst >> 8], 1);
        a.part[slot] = make_uint2(((unsigned)dst << 16) | (unsigned)src, __float_as_uint(w));
    }
}

// --------- k_bucket: per-bucket deg/dinv/offs + local CSR placement (all LDS) ------
__global__ __launch_bounds__(256) void k_bucket(MArgs a) {
    __shared__ float degf[256];
    __shared__ int cnte[256];
    __shared__ int scn[256];
    __shared__ int cur2[256];
    int t = threadIdx.x;
    int b = blockIdx.x;
    degf[t] = 0.f;
    cnte[t] = 0;
    __syncthreads();
    int s0 = a.bbase[b];
    int s1 = a.bbase[b + 1];
    for (int i = s0 + t; i < s1; i += 256) {
        uint2 pp = a.part[i];
        int dl = (pp.x >> 16) & 255;
        atomicAdd(&degf[dl], __uint_as_float(pp.y));
        atomicAdd(&cnte[dl], 1);
    }
    __syncthreads();
    int v = cnte[t];
    scn[t] = v;
    __syncthreads();
    for (int off = 1; off < 256; off <<= 1) {
        int x = (t >= off) ? scn[t - off] : 0;
        __syncthreads();
        scn[t] += x;
        __syncthreads();
    }
    int node = b * 256 + t;
    int base = s0 + scn[t] - v;     // exclusive
    if (node < a.N) {
        float d = degf[t];
        a.dinv[node] = (d > 0.f) ? rsqrtf(fmaxf(d, 1e-30f)) : 0.f;
        a.offs[node] = base;
    }
    if (b == 0 && t == 0) a.offs[a.N] = a.E;
    cur2[t] = base;
    __syncthreads();
    for (int i = s0 + t; i < s1; i += 256) {
        uint2 pp = a.part[i];
        int dl = (pp.x >> 16) & 255;
        unsigned src = pp.x & 0xffffu;
        int slot = atomicAdd(&cur2[dl], 1);
        a.csr[slot] = (src << 16) | (unsigned)f2b(__uint_as_float(pp.y));
    }
}

// --------- hop: node-per-wave, 16 edges in flight, 16B row gathers -----------------
// Tail slots use ed=0 (weight bf16(0)=0, gather hits row 0 -> L1). FIX (hop1):
// apply dinv[src] on the fly and write fixed weights back in place.
template<bool FIX>
__device__ void ph_hop(const MArgs& a, const unsigned short* __restrict__ hin,
                       unsigned short* __restrict__ hout) {
    int lane = threadIdx.x & 63;
    int gq = lane >> 4, fl = lane & 15;
    int node = blockIdx.x * 4 + (threadIdx.x >> 6);
    if (node >= a.N) return;
    int e0 = a.offs[node], e1 = a.offs[node + 1];
    float acc[8] = {};
    for (int j = e0; j < e1; j += 16) {
        int base = j + gq * 4;
        unsigned ed0 = (base + 0 < e1) ? a.csr[base + 0] : 0u;
        unsigned ed1 = (base + 1 < e1) ? a.csr[base + 1] : 0u;
        unsigned ed2 = (base + 2 < e1) ? a.csr[base + 2] : 0u;
        unsigned ed3 = (base + 3 < e1) ? a.csr[base + 3] : 0u;
        float w0 = b2f((unsigned short)(ed0 & 0xffffu));
        float w1 = b2f((unsigned short)(ed1 & 0xffffu));
        float w2 = b2f((unsigned short)(ed2 & 0xffffu));
        float w3 = b2f((unsigned short)(ed3 & 0xffffu));
        if (FIX) {
            w0 *= a.dinv[ed0 >> 16];
            w1 *= a.dinv[ed1 >> 16];
            w2 *= a.dinv[ed2 >> 16];
            w3 *= a.dinv[ed3 >> 16];
        }
        short8 h0 = *(const short8*)(hin + (size_t)(ed0 >> 16) * 128 + fl * 8);
        short8 h1 = *(const short8*)(hin + (size_t)(ed1 >> 16) * 128 + fl * 8);
        short8 h2 = *(const short8*)(hin + (size_t)(ed2 >> 16) * 128 + fl * 8);
        short8 h3 = *(const short8*)(hin + (size_t)(ed3 >> 16) * 128 + fl * 8);
        if (FIX && fl < 4) {
            int wi = base + fl;
            if (wi < e1) {
                float wf2 = (fl == 0) ? w0 : (fl == 1) ? w1 : (fl == 2) ? w2 : w3;
                unsigned ede = (fl == 0) ? ed0 : (fl == 1) ? ed1 : (fl == 2) ? ed2 : ed3;
                a.csr[wi] = (ede & 0xffff0000u) | (unsigned)f2b(wf2);
            }
        }
        #pragma unroll
        for (int k = 0; k < 8; ++k) {
            acc[k] += w0 * b2f((unsigned short)h0[k]) + w1 * b2f((unsigned short)h1[k]);
            acc[k] += w2 * b2f((unsigned short)h2[k]) + w3 * b2f((unsigned short)h3[k]);
        }
    }
    #pragma unroll
    for (int k = 0; k < 8; ++k) {
        acc[k] += __shfl_xor(acc[k], 16);
        acc[k] += __shfl_xor(acc[k], 32);
    }
    if (lane < 16) {
        float dd = a.dinv[node];
        short8 o;
        #pragma unroll
        for (int k = 0; k < 8; ++k) o[k] = (short)f2b(acc[k] * dd);
        *(short8*)(hout + (size_t)node * 128 + fl * 8) = o;
    }
}

template<int H>
__global__ __launch_bounds__(256) void k_hop(MArgs a) {
    const unsigned short* hin = a.hcat + (size_t)(H - 1) * a.NF;
    unsigned short* hout = a.hcat + (size_t)H * a.NF;
    if constexpr (H == 1) ph_hop<true>(a, hin, hout);
    else ph_hop<false>(a, hin, hout);
}

// --------- k_hopgemm: hop3 (node-per-wave, 16 in flight -> LDS As3) + GEMM + stats -
// Phase 1 mirrors the standalone hop's MLP structure (16 gathers in flight/wave),
// writing h3 straight into the swizzled LDS A-tile: kills the 12.8 MB hs3 write +
// 12.8 MB re-read and one dispatch. Phase 2 = R5 gemm; segment 3 reads As3.
__global__ __launch_bounds__(256) void k_hopgemm(MArgs a) {
    __shared__ unsigned short As[2][4096];    // staging tile [wr][32*128]
    __shared__ unsigned short As3[2][4096];   // h3 tile      [wr][32*128]
    const unsigned short* __restrict__ hcat = a.hcat;
    const unsigned short* __restrict__ hs2 = a.hcat + 2 * a.NF;
    const unsigned short* __restrict__ Wf = a.Wf;
    const float* bias = a.tb;
    int M = a.N;
    size_t NF = a.NF;
    int lane = threadIdx.x & 63;
    int wid = threadIdx.x >> 6;
    int wr = wid & 1, wc = wid >> 1;
    int quad = lane >> 4, l15 = lane & 15;
    int row0 = blockIdx.x * 64;

    // ---- phase 1: hop3 for rows [row0, row0+64), node-per-wave ----
    for (int it = 0; it < 16; ++it) {
        int ndl = wid * 16 + it;               // 0..63
        int nd = row0 + ndl;
        float hacc[8] = {};
        if (nd < M) {
            int e0 = a.offs[nd], e1 = a.offs[nd + 1];
            for (int j = e0; j < e1; j += 16) {
                int base = j + quad * 4;
                unsigned ed0 = (base + 0 < e1) ? a.csr[base + 0] : 0u;
                unsigned ed1 = (base + 1 < e1) ? a.csr[base + 1] : 0u;
                unsigned ed2 = (base + 2 < e1) ? a.csr[base + 2] : 0u;
                unsigned ed3 = (base + 3 < e1) ? a.csr[base + 3] : 0u;
                float w0 = b2f((unsigned short)(ed0 & 0xffffu));
                float w1 = b2f((unsigned short)(ed1 & 0xffffu));
                float w2 = b2f((unsigned short)(ed2 & 0xffffu));
                float w3 = b2f((unsigned short)(ed3 & 0xffffu));
                short8 h0 = *(const short8*)(hs2 + (size_t)(ed0 >> 16) * 128 + l15 * 8);
                short8 h1 = *(const short8*)(hs2 + (size_t)(ed1 >> 16) * 128 + l15 * 8);
                short8 h2 = *(const short8*)(hs2 + (size_t)(ed2 >> 16) * 128 + l15 * 8);
                short8 h3 = *(const short8*)(hs2 + (size_t)(ed3 >> 16) * 128 + l15 * 8);
                #pragma unroll
                for (int k = 0; k < 8; ++k) {
                    hacc[k] += w0 * b2f((unsigned short)h0[k]) + w1 * b2f((unsigned short)h1[k]);
                    hacc[k] += w2 * b2f((unsigned short)h2[k]) + w3 * b2f((unsigned short)h3[k]);
                }
            }
        }
        #pragma unroll
        for (int k = 0; k < 8; ++k) {
            hacc[k] += __shfl_xor(hacc[k], 16);
            hacc[k] += __shfl_xor(hacc[k], 32);
        }
        if (lane < 16) {
            float dd = (nd < M) ? a.dinv[nd] : 0.f;
            short8 o;
            #pragma unroll
            for (int k = 0; k < 8; ++k) o[k] = (short)f2b(hacc[k] * dd);
            int rr = ndl & 31;
            *(short8*)&As3[ndl >> 5][(rr * 16 + (l15 ^ (rr & 15))) * 8] = o;
        }
    }
    __syncthreads();                           // As3 complete

    // ---- phase 2: GEMM; segments 0..2 staged from global, segment 3 from As3 ----
    f32x4 acc[2][4] = {};
    short8 stg[4];
    #pragma unroll
    for (int i = 0; i < 4; ++i) {              // prologue: segment 0 loads
        int flat = (wc * 4 + i) * 64 + lane;
        int r = flat >> 4, c = flat & 15;
        stg[i] = *(const short8*)(hcat + (size_t)(row0 + wr * 32 + r) * 128 + c * 8);
    }
    for (int s = 0; s < 4; ++s) {
        const unsigned short* AsP;
        if (s < 3) {
            __syncthreads();                   // prev segment LDS reads done
            #pragma unroll
            for (int i = 0; i < 4; ++i) {
                int flat = (wc * 4 + i) * 64 + lane;
                int r = flat >> 4, c = flat & 15;
                *(short8*)&As[wr][(r * 16 + (c ^ (r & 15))) * 8] = stg[i];
            }
            __syncthreads();                   // tile staged
            if (s < 2) {                       // prefetch next global segment
                const unsigned short* Aseg = hcat + (size_t)(s + 1) * NF;
                #pragma unroll
                for (int i = 0; i < 4; ++i) {
                    int flat = (wc * 4 + i) * 64 + lane;
                    int r = flat >> 4, c = flat & 15;
                    stg[i] = *(const short8*)(Aseg + (size_t)(row0 + wr * 32 + r) * 128 + c * 8);
                }
            }
            AsP = As[wr];
        } else {
            AsP = As3[wr];
        }
        #pragma unroll
        for (int kb = 0; kb < 4; ++kb) {
            int swz = ((kb * 4 + quad) ^ l15) * 8;
            short8 a0 = *(const short8*)&AsP[l15 * 128 + swz];
            short8 a1 = *(const short8*)&AsP[(16 + l15) * 128 + swz];
            const unsigned short* bb = Wf + (size_t)(((s * 4 + kb) * 2 + wc) * 4) * 512 + lane * 8;
            short8 b0 = *(const short8*)(bb + 0 * 512);
            short8 b1 = *(const short8*)(bb + 1 * 512);
            short8 b2 = *(const short8*)(bb + 2 * 512);
            short8 b3 = *(const short8*)(bb + 3 * 512);
            acc[0][0] = __builtin_amdgcn_mfma_f32_16x16x32_bf16(a0, b0, acc[0][0], 0, 0, 0);
            acc[0][1] = __builtin_amdgcn_mfma_f32_16x16x32_bf16(a0, b1, acc[0][1], 0, 0, 0);
            acc[0][2] = __builtin_amdgcn_mfma_f32_16x16x32_bf16(a0, b2, acc[0][2], 0, 0, 0);
            acc[0][3] = __builtin_amdgcn_mfma_f32_16x16x32_bf16(a0, b3, acc[0][3], 0, 0, 0);
            acc[1][0] = __builtin_amdgcn_mfma_f32_16x16x32_bf16(a1, b0, acc[1][0], 0, 0, 0);
            acc[1][1] = __builtin_amdgcn_mfma_f32_16x16x32_bf16(a1, b1, acc[1][1], 0, 0, 0);
            acc[1][2] = __builtin_amdgcn_mfma_f32_16x16x32_bf16(a1, b2, acc[1][2], 0, 0, 0);
            acc[1][3] = __builtin_amdgcn_mfma_f32_16x16x32_bf16(a1, b3, acc[1][3], 0, 0, 0);
        }
    }

    // ---- epilogue: write bf16 out, accumulate per-graph S1/S2 ----
    float bcol[4];
    #pragma unroll
    for (int nt = 0; nt < 4; ++nt) bcol[nt] = bias[wc * 64 + nt * 16 + l15];
    int rg[2][4];
    #pragma unroll
    for (int mt = 0; mt < 2; ++mt) {
        #pragma unroll
        for (int r = 0; r < 4; ++r) {
            int row = row0 + wr * 32 + mt * 16 + quad * 4 + r;
            rg[mt][r] = (row < M) ? a.batch[row] : -1;
            if (row < M) {
                #pragma unroll
                for (int nt = 0; nt < 4; ++nt) {
                    float vv = acc[mt][nt][r] + bcol[nt];
                    a.outb[(size_t)row * 128 + wc * 64 + nt * 16 + l15] = f2b(vv);
                }
            }
        }
    }
    int glo = a.batch[row0];
    int ghi = a.batch[min(row0 + 63, M - 1)];
    for (int g = glo; g <= ghi; ++g) {
        float s1[4] = {0.f, 0.f, 0.f, 0.f}, s2[4] = {0.f, 0.f, 0.f, 0.f};
        #pragma unroll
        for (int mt = 0; mt < 2; ++mt) {
            #pragma unroll
            for (int r = 0; r < 4; ++r) {
                if (rg[mt][r] == g) {
                    #pragma unroll
                    for (int nt = 0; nt < 4; ++nt) {
                        float vv = acc[mt][nt][r] + bcol[nt];
                        s1[nt] += vv;
                        s2[nt] += vv * vv;
                    }
                }
            }
        }
        #pragma unroll
        for (int nt = 0; nt < 4; ++nt) {
            s1[nt] += __shfl_xor(s1[nt], 16);
            s1[nt] += __shfl_xor(s1[nt], 32);
            s2[nt] += __shfl_xor(s2[nt], 16);
            s2[nt] += __shfl_xor(s2[nt], 32);
        }
        if (quad == 0) {
            #pragma unroll
            for (int nt = 0; nt < 4; ++nt) {
                int col = wc * 64 + nt * 16 + l15;
                atomicAdd(&a.S1[g * 128 + col], s1[nt]);
                atomicAdd(&a.S2[g * 128 + col], s2[nt]);
            }
        }
    }
}

// --------- k_final: finalize + graphnorm + relu + residual -------------------------
__global__ __launch_bounds__(256) void k_final(MArgs a) {
    int total = a.N * 32;
    const ushort4* yb = (const ushort4*)a.hcat;      // hs0
    const ushort4* ob = (const ushort4*)a.outb;
    float4* res = (float4*)a.res;
    int idx = blockIdx.x * 256 + threadIdx.x;
    if (idx >= total) return;
    int node = idx >> 5;
    int q = idx & 31;
    int g = a.batch[node];
    float rc = 1.f / fmaxf((float)(a.gstart[g + 1] - a.gstart[g]), 1.f);
    int base = g * 128 + q * 4;
    float4 s1 = *(const float4*)&a.S1[base];
    float4 s2 = *(const float4*)&a.S2[base];
    float4 w  = *(const float4*)&a.gnw[q * 4];
    float4 bb = *(const float4*)&a.gnb[q * 4];
    float4 sc = *(const float4*)&a.gms[q * 4];
    ushort4 yv = yb[idx];
    ushort4 ov = ob[idx];
    float4 r;
    {
        float m = s1.x * rc, e2 = s2.x * rc, s = sc.x;
        float var = e2 - (2.f * s - s * s) * m * m;
        float A = w.x * rsqrtf(var + GN_EPS);
        r.x = b2f(yv.x) + fmaxf(0.f, (b2f(ov.x) - s * m) * A + bb.x);
    }
    {
        float m = s1.y * rc, e2 = s2.y * rc, s = sc.y;
        float var = e2 - (2.f * s - s * s) * m * m;
        float A = w.y * rsqrtf(var + GN_EPS);
        r.y = b2f(yv.y) + fmaxf(0.f, (b2f(ov.y) - s * m) * A + bb.y);
    }
    {
        float m = s1.z * rc, e2 = s2.z * rc, s = sc.z;
        float var = e2 - (2.f * s - s * s) * m * m;
        float A = w.z * rsqrtf(var + GN_EPS);
        r.z = b2f(yv.z) + fmaxf(0.f, (b2f(ov.z) - s * m) * A + bb.z);
    }
    {
        float m = s1.w * rc, e2 = s2.w * rc, s = sc.w;
        float var = e2 - (2.f * s - s * s) * m * m;
        float A = w.w * rsqrtf(var + GN_EPS);
        r.w = b2f(yv.w) + fmaxf(0.f, (b2f(ov.w) - s * m) * A + bb.w);
    }
    res[idx] = r;
}

extern "C" void kernel_launch(void* const* d_in, const int* in_sizes, int n_in,
                              void* d_out, int out_size, void* d_ws, size_t ws_size,
                              hipStream_t stream) {
    const float* y     = (const float*)d_in[0];
    const int*   ei    = (const int*)d_in[1];
    const float* ew    = (const float*)d_in[2];
    const int*   batch = (const int*)d_in[3];
    const float* tag_w = (const float*)d_in[4];
    const float* tag_b = (const float*)d_in[5];
    const float* gnw   = (const float*)d_in[6];
    const float* gnb   = (const float*)d_in[7];
    const float* gms   = (const float*)d_in[8];

    const int N = in_sizes[0] / F;
    const int E = in_sizes[1] / 2;
    const size_t NF = (size_t)N * F;
    const int NB = (N + 255) >> 8;           // dst buckets of 256 nodes
    const int NH = NB * PB;                  // histogram entries
    const int chunk = (E + PB - 1) / PB;
    const int fb = (N * 32 + 255) / 256;
    const int gb = (N + 255) / 256;

    // ---- workspace layout (no memset: S1/S2 zeroed in k_prep) ----
    char* p = (char*)d_ws;
    float* S1 = (float*)p;       p += (size_t)GRAPHS * F * 4;
    float* S2 = (float*)p;       p += (size_t)GRAPHS * F * 4;   // contiguous after S1
    int*   gstart = (int*)p;     p += 512;
    float* dinv = (float*)p;     p += (size_t)N * 4;
    int*   offs = (int*)p;       p += (size_t)(N + 4) * 4;
    int*   hist_t = (int*)p;     p += (size_t)NH * 4;
    int*   bbase = (int*)p;      p += 1040;
    uint2* part = (uint2*)p;     p += (size_t)E * 8;
    unsigned* csr = (unsigned*)p; p += (size_t)E * 4;
    unsigned short* Wf = (unsigned short*)p; p += 4 * 128 * 128 * 2;
    unsigned short* hcat = (unsigned short*)p; p += NF * 2 * 3;   // hs0|hs1|hs2
    unsigned short* outb = (unsigned short*)p; p += NF * 2;        // bf16; OOB-read pad
    p += 4096;

    MArgs ha;
    ha.y = y; ha.ei = ei; ha.ew = ew; ha.batch = batch;
    ha.tw = tag_w; ha.tb = tag_b; ha.gnw = gnw; ha.gnb = gnb; ha.gms = gms;
    ha.res = (float*)d_out;
    ha.S1 = S1; ha.S2 = S2; ha.gstart = gstart; ha.dinv = dinv; ha.offs = offs;
    ha.hist_t = hist_t; ha.bbase = bbase; ha.part = part; ha.csr = csr;
    ha.Wf = Wf; ha.hcat = hcat; ha.outb = outb;
    ha.N = N; ha.E = E; ha.NB = NB; ha.chunk = chunk; ha.fb = fb; ha.gb = gb;
    ha.NF = NF;

    k_prep<<<256 + fb + 256 + gb + 8, 256, 0, stream>>>(ha);
    k_part<<<PB, 256, 0, stream>>>(ha);
    k_bucket<<<NB, 256, 0, stream>>>(ha);
    k_hop<1><<<(N + 3) / 4, 256, 0, stream>>>(ha);
    k_hop<2><<<(N + 3) / 4, 256, 0, stream>>>(ha);
    k_hopgemm<<<(N + 63) / 64, 256, 0, stream>>>(ha);
    k_final<<<(N * 32 + 255) / 256, 256, 0, stream>>>(ha);
}

// Round 7
// 244.920 us; speedup vs baseline: 1.0476x; 1.0476x over previous
//
#include <hip/hip_runtime.h>

#define F 128
#define GRAPHS 64
#define GN_EPS 1e-5f
#define PB 256          // partition blocks / histogram chunks
#define SCAN_B 256
#define CSRBUF 6144     // LDS csr staging (bucket size ~Poisson(3189), 52 sigma margin)

typedef short short8 __attribute__((ext_vector_type(8)));
typedef float f32x4 __attribute__((ext_vector_type(4)));

__device__ __forceinline__ unsigned short f2b(float f) {      // fp32 -> bf16 RNE
    unsigned u = __float_as_uint(f);
    unsigned r = (u + 0x7fffu + ((u >> 16) & 1u)) >> 16;
    return (unsigned short)r;
}
__device__ __forceinline__ float b2f(unsigned short h) {      // bf16 -> fp32
    return __uint_as_float(((unsigned)h) << 16);
}

struct MArgs {
    const float* y; const int* ei; const float* ew; const int* batch;
    const float* tw; const float* tb; const float* gnw; const float* gnb; const float* gms;
    float* res;
    float* S1; float* S2; int* gstart; float* dinv; int* offs; int* hist_t; int* ex;
    int* blockSums; int* bbase;
    uint2* part; unsigned* csr; unsigned short* Wf; unsigned short* hcat; unsigned short* outb;
    int N, E, NB, chunk, fb, gb;
    size_t NF;
};

// ---------------- k_prep: hist | f2b | wcvt | gstart | zero S1/S2 -----------------
__global__ __launch_bounds__(256) void k_prep(MArgs a) {
    __shared__ int hist[256];
    const int t0 = 256;            // hist tasks
    const int t1 = t0 + a.fb;      // f2b tasks
    const int t2 = t1 + 256;       // wcvt tasks (65536 elems)
    const int t3 = t2 + a.gb;      // gstart tasks
    int tid = threadIdx.x;
    int task = blockIdx.x;
    if (task < t0) {                               // ---- per-chunk dst-bucket histogram
        hist[tid] = 0;
        __syncthreads();
        int e0 = task * a.chunk, e1 = min(e0 + a.chunk, a.E);
        for (int e = e0 + tid; e < e1; e += 256)
            atomicAdd(&hist[a.ei[a.E + e] >> 8], 1);
        __syncthreads();
        for (int k = tid; k < a.NB; k += 256)
            a.hist_t[k * PB + task] = hist[k];
    } else if (task < t1) {                        // ---- y fp32 -> bf16 (hs0)
        int i = (task - t0) * 256 + tid;
        if (i < a.N * 32) {
            float4 v = ((const float4*)a.y)[i];
            ((ushort4*)a.hcat)[i] = make_ushort4(f2b(v.x), f2b(v.y), f2b(v.z), f2b(v.w));
        }
    } else if (task < t2) {                        // ---- weight convert/permute
        int i = (task - t1) * 256 + tid;
        int seg = i >> 14;
        int r = i & 16383;
        int kb = r >> 12;
        int wcc = (r >> 11) & 1;
        int ntt = (r >> 9) & 3;
        int lane = (r >> 3) & 63;
        int j = i & 7;
        int k = kb * 32 + (lane >> 4) * 8 + j;
        int nn = wcc * 64 + ntt * 16 + (lane & 15);
        a.Wf[i] = f2b(a.tw[seg * 16384 + k * 128 + nn]);
    } else if (task < t3) {                        // ---- gstart (batch is sorted)
        int i = (task - t2) * 256 + tid;
        if (i < a.N) {
            int bb = a.batch[i];
            if (i == 0) {
                for (int g = 0; g <= bb; ++g) a.gstart[g] = 0;
            } else {
                int bp = a.batch[i - 1];
                for (int g = bp + 1; g <= bb; ++g) a.gstart[g] = i;
            }
            if (i == a.N - 1) {
                for (int g = bb + 1; g <= GRAPHS; ++g) a.gstart[g] = a.N;
            }
        }
    } else {                                       // ---- zero S1/S2 (contiguous)
        int z = task - t3;
        float* dst = a.S1 + z * 2048;
        for (int i2 = tid; i2 < 2048; i2 += 256) dst[i2] = 0.f;
    }
}

// ---------- k_scanA: block-local exclusive scan + blockSums over hist_t ------------
__global__ void k_scanA(MArgs a) {
    __shared__ int s[SCAN_B];
    int n = a.NB * PB;
    int i = blockIdx.x * SCAN_B + threadIdx.x;
    int v = (i < n) ? a.hist_t[i] : 0;
    s[threadIdx.x] = v;
    __syncthreads();
    for (int off = 1; off < SCAN_B; off <<= 1) {
        int t = (threadIdx.x >= off) ? s[threadIdx.x - off] : 0;
        __syncthreads();
        s[threadIdx.x] += t;
        __syncthreads();
    }
    if (i < n) a.ex[i] = s[threadIdx.x] - v;
    if (threadIdx.x == SCAN_B - 1) a.blockSums[blockIdx.x] = s[SCAN_B - 1];
}

// ---------- k_scanB: inline blockSums scan + add (nb <= 256) ----------
__global__ void k_scanB(MArgs a) {
    __shared__ int s[SCAN_B];
    int n = a.NB * PB;
    int nb = (n + SCAN_B - 1) / SCAN_B;
    int t = threadIdx.x;
    int v = (t < nb) ? a.blockSums[t] : 0;
    s[t] = v;
    __syncthreads();
    for (int off = 1; off < SCAN_B; off <<= 1) {
        int x = (t >= off) ? s[t - off] : 0;
        __syncthreads();
        s[t] += x;
        __syncthreads();
    }
    int pre = (blockIdx.x == 0) ? 0 : s[blockIdx.x - 1];
    int i = blockIdx.x * SCAN_B + t;
    if (i < n) a.ex[i] += pre;
}

// --------- k_part: partition edges into dst-buckets (cursors from scanned ex) ------
__global__ __launch_bounds__(256) void k_part(MArgs a) {
    __shared__ int cur[256];
    int t = threadIdx.x;
    int k = blockIdx.x;
    cur[t] = (t < a.NB) ? a.ex[t * PB + k] : 0;
    if (k == 0) {
        if (t < a.NB) a.bbase[t] = a.ex[t * PB];
        if (t == 0) a.bbase[a.NB] = a.E;
    }
    __syncthreads();
    int e0 = k * a.chunk, e1 = min(e0 + a.chunk, a.E);
    for (int e = e0 + t; e < e1; e += 256) {
        int dst = a.ei[a.E + e];
        int src = a.ei[e];
        float w = a.ew[e];
        int slot = atomicAdd(&cur[dst >> 8], 1);
        a.part[slot] = make_uint2(((unsigned)dst << 16) | (unsigned)src, __float_as_uint(w));
    }
}

// --------- k_bucket: per-bucket deg/dinv/offs + LDS-staged CSR placement -----------
// csr writes staged in LDS then copied linearly: kills 64B-sector write
// amplification of the scattered per-cursor 4B stores.
__global__ __launch_bounds__(256) void k_bucket(MArgs a) {
    __shared__ float degf[256];
    __shared__ int cnte[256];
    __shared__ int scn[256];
    __shared__ int cur2[256];
    __shared__ unsigned csrb[CSRBUF];
    int t = threadIdx.x;
    int b = blockIdx.x;
    degf[t] = 0.f;
    cnte[t] = 0;
    __syncthreads();
    int s0 = a.bbase[b];
    int s1 = a.bbase[b + 1];
    for (int i = s0 + t; i < s1; i += 256) {
        uint2 pp = a.part[i];
        int dl = (pp.x >> 16) & 255;
        atomicAdd(&degf[dl], __uint_as_float(pp.y));
        atomicAdd(&cnte[dl], 1);
    }
    __syncthreads();
    int v = cnte[t];
    scn[t] = v;
    __syncthreads();
    for (int off = 1; off < 256; off <<= 1) {
        int x = (t >= off) ? scn[t - off] : 0;
        __syncthreads();
        scn[t] += x;
        __syncthreads();
    }
    int node = b * 256 + t;
    int base = s0 + scn[t] - v;     // exclusive
    if (node < a.N) {
        float d = degf[t];
        a.dinv[node] = (d > 0.f) ? rsqrtf(fmaxf(d, 1e-30f)) : 0.f;
        a.offs[node] = base;
    }
    if (b == 0 && t == 0) a.offs[a.N] = a.E;
    cur2[t] = base;
    __syncthreads();
    for (int i = s0 + t; i < s1; i += 256) {
        uint2 pp = a.part[i];
        int dl = (pp.x >> 16) & 255;
        unsigned src = pp.x & 0xffffu;
        int slot = atomicAdd(&cur2[dl], 1);
        unsigned val = (src << 16) | (unsigned)f2b(__uint_as_float(pp.y));
        int loc = slot - s0;
        if (loc < CSRBUF) csrb[loc] = val;
        else a.csr[slot] = val;                    // overflow guard (never for this input)
    }
    __syncthreads();
    int len = min(s1 - s0, CSRBUF);
    for (int i = t; i < len; i += 256)
        a.csr[s0 + i] = csrb[i];
}

// --------- hop: node-per-wave, 16 edges in flight, 16B row gathers -----------------
// Tail slots use ed=0 (weight bf16(0)=0, gather hits row 0 -> L1). FIX (hop1):
// apply dinv[src] on the fly and write fixed weights back in place.
template<bool FIX>
__device__ void ph_hop(const MArgs& a, const unsigned short* __restrict__ hin,
                       unsigned short* __restrict__ hout) {
    int lane = threadIdx.x & 63;
    int gq = lane >> 4, fl = lane & 15;
    int node = blockIdx.x * 4 + (threadIdx.x >> 6);
    if (node >= a.N) return;
    int e0 = a.offs[node], e1 = a.offs[node + 1];
    float acc[8] = {};
    for (int j = e0; j < e1; j += 16) {
        int base = j + gq * 4;
        unsigned ed0 = (base + 0 < e1) ? a.csr[base + 0] : 0u;
        unsigned ed1 = (base + 1 < e1) ? a.csr[base + 1] : 0u;
        unsigned ed2 = (base + 2 < e1) ? a.csr[base + 2] : 0u;
        unsigned ed3 = (base + 3 < e1) ? a.csr[base + 3] : 0u;
        float w0 = b2f((unsigned short)(ed0 & 0xffffu));
        float w1 = b2f((unsigned short)(ed1 & 0xffffu));
        float w2 = b2f((unsigned short)(ed2 & 0xffffu));
        float w3 = b2f((unsigned short)(ed3 & 0xffffu));
        if (FIX) {
            w0 *= a.dinv[ed0 >> 16];
            w1 *= a.dinv[ed1 >> 16];
            w2 *= a.dinv[ed2 >> 16];
            w3 *= a.dinv[ed3 >> 16];
        }
        short8 h0 = *(const short8*)(hin + (size_t)(ed0 >> 16) * 128 + fl * 8);
        short8 h1 = *(const short8*)(hin + (size_t)(ed1 >> 16) * 128 + fl * 8);
        short8 h2 = *(const short8*)(hin + (size_t)(ed2 >> 16) * 128 + fl * 8);
        short8 h3 = *(const short8*)(hin + (size_t)(ed3 >> 16) * 128 + fl * 8);
        if (FIX && fl < 4) {
            int wi = base + fl;
            if (wi < e1) {
                float wf2 = (fl == 0) ? w0 : (fl == 1) ? w1 : (fl == 2) ? w2 : w3;
                unsigned ede = (fl == 0) ? ed0 : (fl == 1) ? ed1 : (fl == 2) ? ed2 : ed3;
                a.csr[wi] = (ede & 0xffff0000u) | (unsigned)f2b(wf2);
            }
        }
        #pragma unroll
        for (int k = 0; k < 8; ++k) {
            acc[k] += w0 * b2f((unsigned short)h0[k]) + w1 * b2f((unsigned short)h1[k]);
            acc[k] += w2 * b2f((unsigned short)h2[k]) + w3 * b2f((unsigned short)h3[k]);
        }
    }
    #pragma unroll
    for (int k = 0; k < 8; ++k) {
        acc[k] += __shfl_xor(acc[k], 16);
        acc[k] += __shfl_xor(acc[k], 32);
    }
    if (lane < 16) {
        float dd = a.dinv[node];
        short8 o;
        #pragma unroll
        for (int k = 0; k < 8; ++k) o[k] = (short)f2b(acc[k] * dd);
        *(short8*)(hout + (size_t)node * 128 + fl * 8) = o;
    }
}

template<int H>
__global__ __launch_bounds__(256) void k_hop(MArgs a) {
    const unsigned short* hin = a.hcat + (size_t)(H - 1) * a.NF;
    unsigned short* hout = a.hcat + (size_t)H * a.NF;
    if constexpr (H == 1) ph_hop<true>(a, hin, hout);
    else ph_hop<false>(a, hin, hout);
}

// --------- k_gemm: fused GEMM + bias + per-graph stats (S1, S2) --------------------
// A-tile staged once per wr-half (shared by both wc waves); next segment's global
// loads prefetched before the MFMA loop. Stats from f32 pre-bf16 accumulators.
__global__ __launch_bounds__(256) void k_gemm(MArgs a) {
    __shared__ unsigned short As[2][4096];   // [wr][32*128]
    const unsigned short* __restrict__ hcat = a.hcat;
    const unsigned short* __restrict__ Wf = a.Wf;
    const float* bias = a.tb;
    int M = a.N;
    size_t NF = a.NF;
    int lane = threadIdx.x & 63;
    int wid = threadIdx.x >> 6;
    int wr = wid & 1, wc = wid >> 1;
    int quad = lane >> 4, l15 = lane & 15;
    int row0 = blockIdx.x * 64;
    f32x4 acc[2][4] = {};
    short8 stg[4];
    #pragma unroll
    for (int i = 0; i < 4; ++i) {            // prologue: segment 0 loads
        int flat = (wc * 4 + i) * 64 + lane;
        int r = flat >> 4, c = flat & 15;
        stg[i] = *(const short8*)(hcat + (size_t)(row0 + wr * 32 + r) * 128 + c * 8);
    }
    for (int s = 0; s < 4; ++s) {
        __syncthreads();                          // prev segment LDS reads done
        #pragma unroll
        for (int i = 0; i < 4; ++i) {
            int flat = (wc * 4 + i) * 64 + lane;
            int r = flat >> 4, c = flat & 15;
            *(short8*)&As[wr][(r * 16 + (c ^ (r & 15))) * 8] = stg[i];
        }
        __syncthreads();                          // tile staged
        if (s < 3) {                              // prefetch next segment (overlaps MFMA)
            const unsigned short* Aseg = hcat + (size_t)(s + 1) * NF;
            #pragma unroll
            for (int i = 0; i < 4; ++i) {
                int flat = (wc * 4 + i) * 64 + lane;
                int r = flat >> 4, c = flat & 15;
                stg[i] = *(const short8*)(Aseg + (size_t)(row0 + wr * 32 + r) * 128 + c * 8);
            }
        }
        #pragma unroll
        for (int kb = 0; kb < 4; ++kb) {
            int swz = ((kb * 4 + quad) ^ l15) * 8;
            short8 a0 = *(short8*)&As[wr][l15 * 128 + swz];
            short8 a1 = *(short8*)&As[wr][(16 + l15) * 128 + swz];
            const unsigned short* bb = Wf + (size_t)(((s * 4 + kb) * 2 + wc) * 4) * 512 + lane * 8;
            short8 b0 = *(const short8*)(bb + 0 * 512);
            short8 b1 = *(const short8*)(bb + 1 * 512);
            short8 b2 = *(const short8*)(bb + 2 * 512);
            short8 b3 = *(const short8*)(bb + 3 * 512);
            acc[0][0] = __builtin_amdgcn_mfma_f32_16x16x32_bf16(a0, b0, acc[0][0], 0, 0, 0);
            acc[0][1] = __builtin_amdgcn_mfma_f32_16x16x32_bf16(a0, b1, acc[0][1], 0, 0, 0);
            acc[0][2] = __builtin_amdgcn_mfma_f32_16x16x32_bf16(a0, b2, acc[0][2], 0, 0, 0);
            acc[0][3] = __builtin_amdgcn_mfma_f32_16x16x32_bf16(a0, b3, acc[0][3], 0, 0, 0);
            acc[1][0] = __builtin_amdgcn_mfma_f32_16x16x32_bf16(a1, b0, acc[1][0], 0, 0, 0);
            acc[1][1] = __builtin_amdgcn_mfma_f32_16x16x32_bf16(a1, b1, acc[1][1], 0, 0, 0);
            acc[1][2] = __builtin_amdgcn_mfma_f32_16x16x32_bf16(a1, b2, acc[1][2], 0, 0, 0);
            acc[1][3] = __builtin_amdgcn_mfma_f32_16x16x32_bf16(a1, b3, acc[1][3], 0, 0, 0);
        }
    }

    // ---- epilogue: write bf16 out, accumulate per-graph S1/S2 ----
    float bcol[4];
    #pragma unroll
    for (int nt = 0; nt < 4; ++nt) bcol[nt] = bias[wc * 64 + nt * 16 + l15];
    int rg[2][4];
    #pragma unroll
    for (int mt = 0; mt < 2; ++mt) {
        #pragma unroll
        for (int r = 0; r < 4; ++r) {
            int row = row0 + wr * 32 + mt * 16 + quad * 4 + r;
            rg[mt][r] = (row < M) ? a.batch[row] : -1;
            if (row < M) {
                #pragma unroll
                for (int nt = 0; nt < 4; ++nt) {
                    float vv = acc[mt][nt][r] + bcol[nt];
                    a.outb[(size_t)row * 128 + wc * 64 + nt * 16 + l15] = f2b(vv);
                }
            }
        }
    }
    int glo = a.batch[row0];
    int ghi = a.batch[min(row0 + 63, M - 1)];
    for (int g = glo; g <= ghi; ++g) {
        float s1[4] = {0.f, 0.f, 0.f, 0.f}, s2[4] = {0.f, 0.f, 0.f, 0.f};
        #pragma unroll
        for (int mt = 0; mt < 2; ++mt) {
            #pragma unroll
            for (int r = 0; r < 4; ++r) {
                if (rg[mt][r] == g) {
                    #pragma unroll
                    for (int nt = 0; nt < 4; ++nt) {
                        float vv = acc[mt][nt][r] + bcol[nt];
                        s1[nt] += vv;
                        s2[nt] += vv * vv;
                    }
                }
            }
        }
        #pragma unroll
        for (int nt = 0; nt < 4; ++nt) {
            s1[nt] += __shfl_xor(s1[nt], 16);
            s1[nt] += __shfl_xor(s1[nt], 32);
            s2[nt] += __shfl_xor(s2[nt], 16);
            s2[nt] += __shfl_xor(s2[nt], 32);
        }
        if (quad == 0) {
            #pragma unroll
            for (int nt = 0; nt < 4; ++nt) {
                int col = wc * 64 + nt * 16 + l15;
                atomicAdd(&a.S1[g * 128 + col], s1[nt]);
                atomicAdd(&a.S2[g * 128 + col], s2[nt]);
            }
        }
    }
}

// --------- k_final: finalize + graphnorm + relu + residual -------------------------
__global__ __launch_bounds__(256) void k_final(MArgs a) {
    int total = a.N * 32;
    const ushort4* yb = (const ushort4*)a.hcat;      // hs0
    const ushort4* ob = (const ushort4*)a.outb;
    float4* res = (float4*)a.res;
    int idx = blockIdx.x * 256 + threadIdx.x;
    if (idx >= total) return;
    int node = idx >> 5;
    int q = idx & 31;
    int g = a.batch[node];
    float rc = 1.f / fmaxf((float)(a.gstart[g + 1] - a.gstart[g]), 1.f);
    int base = g * 128 + q * 4;
    float4 s1 = *(const float4*)&a.S1[base];
    float4 s2 = *(const float4*)&a.S2[base];
    float4 w  = *(const float4*)&a.gnw[q * 4];
    float4 bb = *(const float4*)&a.gnb[q * 4];
    float4 sc = *(const float4*)&a.gms[q * 4];
    ushort4 yv = yb[idx];
    ushort4 ov = ob[idx];
    float4 r;
    {
        float m = s1.x * rc, e2 = s2.x * rc, s = sc.x;
        float var = e2 - (2.f * s - s * s) * m * m;
        float A = w.x * rsqrtf(var + GN_EPS);
        r.x = b2f(yv.x) + fmaxf(0.f, (b2f(ov.x) - s * m) * A + bb.x);
    }
    {
        float m = s1.y * rc, e2 = s2.y * rc, s = sc.y;
        float var = e2 - (2.f * s - s * s) * m * m;
        float A = w.y * rsqrtf(var + GN_EPS);
        r.y = b2f(yv.y) + fmaxf(0.f, (b2f(ov.y) - s * m) * A + bb.y);
    }
    {
        float m = s1.z * rc, e2 = s2.z * rc, s = sc.z;
        float var = e2 - (2.f * s - s * s) * m * m;
        float A = w.z * rsqrtf(var + GN_EPS);
        r.z = b2f(yv.z) + fmaxf(0.f, (b2f(ov.z) - s * m) * A + bb.z);
    }
    {
        float m = s1.w * rc, e2 = s2.w * rc, s = sc.w;
        float var = e2 - (2.f * s - s * s) * m * m;
        float A = w.w * rsqrtf(var + GN_EPS);
        r.w = b2f(yv.w) + fmaxf(0.f, (b2f(ov.w) - s * m) * A + bb.w);
    }
    res[idx] = r;
}

extern "C" void kernel_launch(void* const* d_in, const int* in_sizes, int n_in,
                              void* d_out, int out_size, void* d_ws, size_t ws_size,
                              hipStream_t stream) {
    const float* y     = (const float*)d_in[0];
    const int*   ei    = (const int*)d_in[1];
    const float* ew    = (const float*)d_in[2];
    const int*   batch = (const int*)d_in[3];
    const float* tag_w = (const float*)d_in[4];
    const float* tag_b = (const float*)d_in[5];
    const float* gnw   = (const float*)d_in[6];
    const float* gnb   = (const float*)d_in[7];
    const float* gms   = (const float*)d_in[8];

    const int N = in_sizes[0] / F;
    const int E = in_sizes[1] / 2;
    const size_t NF = (size_t)N * F;
    const int NB = (N + 255) >> 8;           // dst buckets of 256 nodes
    const int NH = NB * PB;                  // histogram entries
    const int chunk = (E + PB - 1) / PB;
    const int fb = (N * 32 + 255) / 256;
    const int gb = (N + 255) / 256;

    // ---- workspace layout (no memset: S1/S2 zeroed in k_prep) ----
    char* p = (char*)d_ws;
    float* S1 = (float*)p;       p += (size_t)GRAPHS * F * 4;
    float* S2 = (float*)p;       p += (size_t)GRAPHS * F * 4;   // contiguous after S1
    int*   gstart = (int*)p;     p += 512;
    float* dinv = (float*)p;     p += (size_t)N * 4;
    int*   offs = (int*)p;       p += (size_t)(N + 4) * 4;
    int*   hist_t = (int*)p;     p += (size_t)NH * 4;
    int*   ex = (int*)p;         p += (size_t)(NH + 4) * 4;
    int*   blockSums = (int*)p;  p += 4096;
    int*   bbase = (int*)p;      p += 1040;
    uint2* part = (uint2*)p;     p += (size_t)E * 8;
    unsigned* csr = (unsigned*)p; p += (size_t)E * 4;
    unsigned short* Wf = (unsigned short*)p; p += 4 * 128 * 128 * 2;
    unsigned short* hcat = (unsigned short*)p; p += NF * 2 * 4;   // 4 bf16 slices
    unsigned short* outb = (unsigned short*)p; p += NF * 2;        // bf16; OOB-read pad
    p += 4096;

    MArgs ha;
    ha.y = y; ha.ei = ei; ha.ew = ew; ha.batch = batch;
    ha.tw = tag_w; ha.tb = tag_b; ha.gnw = gnw; ha.gnb = gnb; ha.gms = gms;
    ha.res = (float*)d_out;
    ha.S1 = S1; ha.S2 = S2; ha.gstart = gstart; ha.dinv = dinv; ha.offs = offs;
    ha.hist_t = hist_t; ha.ex = ex; ha.blockSums = blockSums; ha.bbase = bbase;
    ha.part = part; ha.csr = csr;
    ha.Wf = Wf; ha.hcat = hcat; ha.outb = outb;
    ha.N = N; ha.E = E; ha.NB = NB; ha.chunk = chunk; ha.fb = fb; ha.gb = gb;
    ha.NF = NF;

    const int hsb = (NH + SCAN_B - 1) / SCAN_B;
    k_prep<<<256 + fb + 256 + gb + 8, 256, 0, stream>>>(ha);
    k_scanA<<<hsb, SCAN_B, 0, stream>>>(ha);
    k_scanB<<<hsb, SCAN_B, 0, stream>>>(ha);
    k_part<<<PB, 256, 0, stream>>>(ha);
    k_bucket<<<NB, 256, 0, stream>>>(ha);
    k_hop<1><<<(N + 3) / 4, 256, 0, stream>>>(ha);
    k_hop<2><<<(N + 3) / 4, 256, 0, stream>>>(ha);
    k_hop<3><<<(N + 3) / 4, 256, 0, stream>>>(ha);
    k_gemm<<<(N + 63) / 64, 256, 0, stream>>>(ha);
    k_final<<<(N * 32 + 255) / 256, 256, 0, stream>>>(ha);
}

// Round 8
// 225.110 us; speedup vs baseline: 1.1398x; 1.0880x over previous
//
#include <hip/hip_runtime.h>

#define F 128
#define GRAPHS 64
#define GN_EPS 1e-5f
#define PB 256          // partition blocks / histogram chunks

typedef short short8 __attribute__((ext_vector_type(8)));
typedef float f32x4 __attribute__((ext_vector_type(4)));

__device__ __forceinline__ unsigned short f2b(float f) {      // fp32 -> bf16 RNE
    unsigned u = __float_as_uint(f);
    unsigned r = (u + 0x7fffu + ((u >> 16) & 1u)) >> 16;
    return (unsigned short)r;
}
__device__ __forceinline__ float b2f(unsigned short h) {      // bf16 -> fp32
    return __uint_as_float(((unsigned)h) << 16);
}

struct MArgs {
    const float* y; const int* ei; const float* ew; const int* batch;
    const float* tw; const float* tb; const float* gnw; const float* gnb; const float* gms;
    float* res;
    float* S1; float* S2; int* gstart; float* dinv; int* offs; int* hist_t; int* bbase;
    uint2* part; unsigned* csr; unsigned short* Wf; unsigned short* hcat; unsigned short* outb;
    int N, E, NB, chunk, fb, gb;
    size_t NF;
};

// ---------------- k_prep: hist | f2b | wcvt | gstart | zero S1/S2 -----------------
__global__ __launch_bounds__(256) void k_prep(MArgs a) {
    __shared__ int hist[256];
    const int t0 = 256;            // hist tasks
    const int t1 = t0 + a.fb;      // f2b tasks
    const int t2 = t1 + 256;       // wcvt tasks (65536 elems)
    const int t3 = t2 + a.gb;      // gstart tasks
    int tid = threadIdx.x;
    int task = blockIdx.x;
    if (task < t0) {                               // ---- per-chunk dst-bucket histogram
        hist[tid] = 0;
        __syncthreads();
        int e0 = task * a.chunk, e1 = min(e0 + a.chunk, a.E);
        for (int e = e0 + tid; e < e1; e += 256)
            atomicAdd(&hist[a.ei[a.E + e] >> 8], 1);
        __syncthreads();
        for (int k = tid; k < a.NB; k += 256)
            a.hist_t[k * PB + task] = hist[k];
    } else if (task < t1) {                        // ---- y fp32 -> bf16 (hs0)
        int i = (task - t0) * 256 + tid;
        if (i < a.N * 32) {
            float4 v = ((const float4*)a.y)[i];
            ((ushort4*)a.hcat)[i] = make_ushort4(f2b(v.x), f2b(v.y), f2b(v.z), f2b(v.w));
        }
    } else if (task < t2) {                        // ---- weight convert/permute
        int i = (task - t1) * 256 + tid;
        int seg = i >> 14;
        int r = i & 16383;
        int kb = r >> 12;
        int wcc = (r >> 11) & 1;
        int ntt = (r >> 9) & 3;
        int lane = (r >> 3) & 63;
        int j = i & 7;
        int k = kb * 32 + (lane >> 4) * 8 + j;
        int nn = wcc * 64 + ntt * 16 + (lane & 15);
        a.Wf[i] = f2b(a.tw[seg * 16384 + k * 128 + nn]);
    } else if (task < t3) {                        // ---- gstart (batch is sorted)
        int i = (task - t2) * 256 + tid;
        if (i < a.N) {
            int bb = a.batch[i];
            if (i == 0) {
                for (int g = 0; g <= bb; ++g) a.gstart[g] = 0;
            } else {
                int bp = a.batch[i - 1];
                for (int g = bp + 1; g <= bb; ++g) a.gstart[g] = i;
            }
            if (i == a.N - 1) {
                for (int g = bb + 1; g <= GRAPHS; ++g) a.gstart[g] = a.N;
            }
        }
    } else {                                       // ---- zero S1/S2 (contiguous)
        int z = task - t3;
        float* dst = a.S1 + z * 2048;
        for (int i2 = tid; i2 < 2048; i2 += 256) dst[i2] = 0.f;
    }
}

// --------- k_part: partition edges into dst-buckets; scan folded in ---------------
__global__ __launch_bounds__(256) void k_part(MArgs a) {
    __shared__ int cur[256];
    __shared__ int rs[256];
    int t = threadIdx.x;
    int k = blockIdx.x;
    int total = 0, pref = 0;
    if (t < a.NB) {
        const int4* row = (const int4*)(a.hist_t + t * PB);
        for (int q = 0; q < PB / 4; ++q) {
            int4 v = row[q];
            int c4 = q * 4;
            total += v.x + v.y + v.z + v.w;
            if (c4 + 4 <= k) pref += v.x + v.y + v.z + v.w;
            else {
                if (c4 + 0 < k) pref += v.x;
                if (c4 + 1 < k) pref += v.y;
                if (c4 + 2 < k) pref += v.z;
                if (c4 + 3 < k) pref += v.w;
            }
        }
    }
    rs[t] = (t < a.NB) ? total : 0;
    __syncthreads();
    for (int off = 1; off < 256; off <<= 1) {       // inclusive scan of row sums
        int x = (t >= off) ? rs[t - off] : 0;
        __syncthreads();
        rs[t] += x;
        __syncthreads();
    }
    int rowStart = (t > 0) ? rs[t - 1] : 0;         // exclusive bucket base
    cur[t] = rowStart + pref;
    if (k == 0 && t <= a.NB) a.bbase[t] = rowStart; // bbase[NB] == E
    __syncthreads();
    int e0 = k * a.chunk, e1 = min(e0 + a.chunk, a.E);
    for (int e = e0 + t; e < e1; e += 256) {
        int dst = a.ei[a.E + e];
        int src = a.ei[e];
        float w = a.ew[e];
        int slot = atomicAdd(&cur[dst >> 8], 1);
        a.part[slot] = make_uint2(((unsigned)dst << 16) | (unsigned)src, __float_as_uint(w));
    }
}

// --------- k_bucket: per-bucket deg/dinv/offs + local CSR placement (all LDS) ------
__global__ __launch_bounds__(256) void k_bucket(MArgs a) {
    __shared__ float degf[256];
    __shared__ int cnte[256];
    __shared__ int scn[256];
    __shared__ int cur2[256];
    int t = threadIdx.x;
    int b = blockIdx.x;
    degf[t] = 0.f;
    cnte[t] = 0;
    __syncthreads();
    int s0 = a.bbase[b];
    int s1 = a.bbase[b + 1];
    for (int i = s0 + t; i < s1; i += 256) {
        uint2 pp = a.part[i];
        int dl = (pp.x >> 16) & 255;
        atomicAdd(&degf[dl], __uint_as_float(pp.y));
        atomicAdd(&cnte[dl], 1);
    }
    __syncthreads();
    int v = cnte[t];
    scn[t] = v;
    __syncthreads();
    for (int off = 1; off < 256; off <<= 1) {
        int x = (t >= off) ? scn[t - off] : 0;
        __syncthreads();
        scn[t] += x;
        __syncthreads();
    }
    int node = b * 256 + t;
    int base = s0 + scn[t] - v;     // exclusive
    if (node < a.N) {
        float d = degf[t];
        a.dinv[node] = (d > 0.f) ? rsqrtf(fmaxf(d, 1e-30f)) : 0.f;
        a.offs[node] = base;
    }
    if (b == 0 && t == 0) a.offs[a.N] = a.E;
    cur2[t] = base;
    __syncthreads();
    for (int i = s0 + t; i < s1; i += 256) {
        uint2 pp = a.part[i];
        int dl = (pp.x >> 16) & 255;
        unsigned src = pp.x & 0xffffu;
        int slot = atomicAdd(&cur2[dl], 1);
        a.csr[slot] = (src << 16) | (unsigned)f2b(__uint_as_float(pp.y));
    }
}

// --------- hop: node-per-wave, 16 edges in flight, 16B row gathers -----------------
// Tail slots use ed=0 (weight bf16(0)=0, gather hits row 0 -> L1). FIX (hop1):
// apply dinv[src] on the fly and write fixed weights back in place.
template<bool FIX>
__device__ void ph_hop(const MArgs& a, const unsigned short* __restrict__ hin,
                       unsigned short* __restrict__ hout) {
    int lane = threadIdx.x & 63;
    int gq = lane >> 4, fl = lane & 15;
    int node = blockIdx.x * 4 + (threadIdx.x >> 6);
    if (node >= a.N) return;
    int e0 = a.offs[node], e1 = a.offs[node + 1];
    float acc[8] = {};
    for (int j = e0; j < e1; j += 16) {
        int base = j + gq * 4;
        unsigned ed0 = (base + 0 < e1) ? a.csr[base + 0] : 0u;
        unsigned ed1 = (base + 1 < e1) ? a.csr[base + 1] : 0u;
        unsigned ed2 = (base + 2 < e1) ? a.csr[base + 2] : 0u;
        unsigned ed3 = (base + 3 < e1) ? a.csr[base + 3] : 0u;
        float w0 = b2f((unsigned short)(ed0 & 0xffffu));
        float w1 = b2f((unsigned short)(ed1 & 0xffffu));
        float w2 = b2f((unsigned short)(ed2 & 0xffffu));
        float w3 = b2f((unsigned short)(ed3 & 0xffffu));
        if (FIX) {
            w0 *= a.dinv[ed0 >> 16];
            w1 *= a.dinv[ed1 >> 16];
            w2 *= a.dinv[ed2 >> 16];
            w3 *= a.dinv[ed3 >> 16];
        }
        short8 h0 = *(const short8*)(hin + (size_t)(ed0 >> 16) * 128 + fl * 8);
        short8 h1 = *(const short8*)(hin + (size_t)(ed1 >> 16) * 128 + fl * 8);
        short8 h2 = *(const short8*)(hin + (size_t)(ed2 >> 16) * 128 + fl * 8);
        short8 h3 = *(const short8*)(hin + (size_t)(ed3 >> 16) * 128 + fl * 8);
        if (FIX && fl < 4) {
            int wi = base + fl;
            if (wi < e1) {
                float wf2 = (fl == 0) ? w0 : (fl == 1) ? w1 : (fl == 2) ? w2 : w3;
                unsigned ede = (fl == 0) ? ed0 : (fl == 1) ? ed1 : (fl == 2) ? ed2 : ed3;
                a.csr[wi] = (ede & 0xffff0000u) | (unsigned)f2b(wf2);
            }
        }
        #pragma unroll
        for (int k = 0; k < 8; ++k) {
            acc[k] += w0 * b2f((unsigned short)h0[k]) + w1 * b2f((unsigned short)h1[k]);
            acc[k] += w2 * b2f((unsigned short)h2[k]) + w3 * b2f((unsigned short)h3[k]);
        }
    }
    #pragma unroll
    for (int k = 0; k < 8; ++k) {
        acc[k] += __shfl_xor(acc[k], 16);
        acc[k] += __shfl_xor(acc[k], 32);
    }
    if (lane < 16) {
        float dd = a.dinv[node];
        short8 o;
        #pragma unroll
        for (int k = 0; k < 8; ++k) o[k] = (short)f2b(acc[k] * dd);
        *(short8*)(hout + (size_t)node * 128 + fl * 8) = o;
    }
}

template<int H>
__global__ __launch_bounds__(256) void k_hop(MArgs a) {
    const unsigned short* hin = a.hcat + (size_t)(H - 1) * a.NF;
    unsigned short* hout = a.hcat + (size_t)H * a.NF;
    if constexpr (H == 1) ph_hop<true>(a, hin, hout);
    else ph_hop<false>(a, hin, hout);
}

// --------- k_gemm: 32-row tiles for 2x occupancy + bias + per-graph stats ----------
// Grid 2x (1563 blocks): gemm was grid-starved at 3 waves/SIMD with 64-row tiles.
// 4 waves/block, each wave owns 32 cols (wc half + nt pair). 8 KB LDS, ~16 fewer
// VGPR/wave. Wf re-read doubles but is L2-hot broadcast (~+3 us). Prefetch kept.
__global__ __launch_bounds__(256) void k_gemm(MArgs a) {
    __shared__ unsigned short As[4096];      // 32 rows x 128 cols, swizzled
    const unsigned short* __restrict__ hcat = a.hcat;
    const unsigned short* __restrict__ Wf = a.Wf;
    const float* bias = a.tb;
    int M = a.N;
    size_t NF = a.NF;
    int lane = threadIdx.x & 63;
    int w = threadIdx.x >> 6;                // wave 0..3, owns cols [w*32, w*32+32)
    int wc = w >> 1;                         // 64-col half (Wf layout)
    int ntb = (w & 1) * 2;                   // nt base within half
    int quad = lane >> 4, l15 = lane & 15;
    int row0 = blockIdx.x * 32;
    f32x4 acc[2][2] = {};                    // [mt][ct]
    short8 stg[2];
    #pragma unroll
    for (int i = 0; i < 2; ++i) {            // prologue: segment 0 loads
        int flat = i * 256 + threadIdx.x;
        int r = flat >> 4, c = flat & 15;
        stg[i] = *(const short8*)(hcat + (size_t)(row0 + r) * 128 + c * 8);
    }
    for (int s = 0; s < 4; ++s) {
        __syncthreads();                     // prev segment LDS reads done
        #pragma unroll
        for (int i = 0; i < 2; ++i) {
            int flat = i * 256 + threadIdx.x;
            int r = flat >> 4, c = flat & 15;
            *(short8*)&As[(r * 16 + (c ^ (r & 15))) * 8] = stg[i];
        }
        __syncthreads();                     // tile staged
        if (s < 3) {                         // prefetch next segment (overlaps MFMA)
            const unsigned short* Aseg = hcat + (size_t)(s + 1) * NF;
            #pragma unroll
            for (int i = 0; i < 2; ++i) {
                int flat = i * 256 + threadIdx.x;
                int r = flat >> 4, c = flat & 15;
                stg[i] = *(const short8*)(Aseg + (size_t)(row0 + r) * 128 + c * 8);
            }
        }
        #pragma unroll
        for (int kb = 0; kb < 4; ++kb) {
            int swz = ((kb * 4 + quad) ^ l15) * 8;
            short8 a0 = *(short8*)&As[l15 * 128 + swz];
            short8 a1 = *(short8*)&As[(16 + l15) * 128 + swz];
            const unsigned short* bb =
                Wf + (size_t)((((s * 4 + kb) * 2 + wc) * 4) + ntb) * 512 + lane * 8;
            short8 b0 = *(const short8*)(bb + 0 * 512);
            short8 b1 = *(const short8*)(bb + 1 * 512);
            acc[0][0] = __builtin_amdgcn_mfma_f32_16x16x32_bf16(a0, b0, acc[0][0], 0, 0, 0);
            acc[0][1] = __builtin_amdgcn_mfma_f32_16x16x32_bf16(a0, b1, acc[0][1], 0, 0, 0);
            acc[1][0] = __builtin_amdgcn_mfma_f32_16x16x32_bf16(a1, b0, acc[1][0], 0, 0, 0);
            acc[1][1] = __builtin_amdgcn_mfma_f32_16x16x32_bf16(a1, b1, acc[1][1], 0, 0, 0);
        }
    }

    // ---- epilogue: write bf16 out, accumulate per-graph S1/S2 ----
    float bcol[2];
    #pragma unroll
    for (int ct = 0; ct < 2; ++ct) bcol[ct] = bias[w * 32 + ct * 16 + l15];
    int rg[2][4];
    #pragma unroll
    for (int mt = 0; mt < 2; ++mt) {
        #pragma unroll
        for (int r = 0; r < 4; ++r) {
            int row = row0 + mt * 16 + quad * 4 + r;
            rg[mt][r] = (row < M) ? a.batch[row] : -1;
            if (row < M) {
                #pragma unroll
                for (int ct = 0; ct < 2; ++ct) {
                    float vv = acc[mt][ct][r] + bcol[ct];
                    a.outb[(size_t)row * 128 + w * 32 + ct * 16 + l15] = f2b(vv);
                }
            }
        }
    }
    int glo = a.batch[row0];
    int ghi = a.batch[min(row0 + 31, M - 1)];
    for (int g = glo; g <= ghi; ++g) {
        float s1[2] = {0.f, 0.f}, s2[2] = {0.f, 0.f};
        #pragma unroll
        for (int mt = 0; mt < 2; ++mt) {
            #pragma unroll
            for (int r = 0; r < 4; ++r) {
                if (rg[mt][r] == g) {
                    #pragma unroll
                    for (int ct = 0; ct < 2; ++ct) {
                        float vv = acc[mt][ct][r] + bcol[ct];
                        s1[ct] += vv;
                        s2[ct] += vv * vv;
                    }
                }
            }
        }
        #pragma unroll
        for (int ct = 0; ct < 2; ++ct) {
            s1[ct] += __shfl_xor(s1[ct], 16);
            s1[ct] += __shfl_xor(s1[ct], 32);
            s2[ct] += __shfl_xor(s2[ct], 16);
            s2[ct] += __shfl_xor(s2[ct], 32);
        }
        if (quad == 0) {
            #pragma unroll
            for (int ct = 0; ct < 2; ++ct) {
                int col = w * 32 + ct * 16 + l15;
                atomicAdd(&a.S1[g * 128 + col], s1[ct]);
                atomicAdd(&a.S2[g * 128 + col], s2[ct]);
            }
        }
    }
}

// --------- k_final: finalize + graphnorm + relu + residual -------------------------
__global__ __launch_bounds__(256) void k_final(MArgs a) {
    int total = a.N * 32;
    const ushort4* yb = (const ushort4*)a.hcat;      // hs0
    const ushort4* ob = (const ushort4*)a.outb;
    float4* res = (float4*)a.res;
    int idx = blockIdx.x * 256 + threadIdx.x;
    if (idx >= total) return;
    int node = idx >> 5;
    int q = idx & 31;
    int g = a.batch[node];
    float rc = 1.f / fmaxf((float)(a.gstart[g + 1] - a.gstart[g]), 1.f);
    int base = g * 128 + q * 4;
    float4 s1 = *(const float4*)&a.S1[base];
    float4 s2 = *(const float4*)&a.S2[base];
    float4 w  = *(const float4*)&a.gnw[q * 4];
    float4 bb = *(const float4*)&a.gnb[q * 4];
    float4 sc = *(const float4*)&a.gms[q * 4];
    ushort4 yv = yb[idx];
    ushort4 ov = ob[idx];
    float4 r;
    {
        float m = s1.x * rc, e2 = s2.x * rc, s = sc.x;
        float var = e2 - (2.f * s - s * s) * m * m;
        float A = w.x * rsqrtf(var + GN_EPS);
        r.x = b2f(yv.x) + fmaxf(0.f, (b2f(ov.x) - s * m) * A + bb.x);
    }
    {
        float m = s1.y * rc, e2 = s2.y * rc, s = sc.y;
        float var = e2 - (2.f * s - s * s) * m * m;
        float A = w.y * rsqrtf(var + GN_EPS);
        r.y = b2f(yv.y) + fmaxf(0.f, (b2f(ov.y) - s * m) * A + bb.y);
    }
    {
        float m = s1.z * rc, e2 = s2.z * rc, s = sc.z;
        float var = e2 - (2.f * s - s * s) * m * m;
        float A = w.z * rsqrtf(var + GN_EPS);
        r.z = b2f(yv.z) + fmaxf(0.f, (b2f(ov.z) - s * m) * A + bb.z);
    }
    {
        float m = s1.w * rc, e2 = s2.w * rc, s = sc.w;
        float var = e2 - (2.f * s - s * s) * m * m;
        float A = w.w * rsqrtf(var + GN_EPS);
        r.w = b2f(yv.w) + fmaxf(0.f, (b2f(ov.w) - s * m) * A + bb.w);
    }
    res[idx] = r;
}

extern "C" void kernel_launch(void* const* d_in, const int* in_sizes, int n_in,
                              void* d_out, int out_size, void* d_ws, size_t ws_size,
                              hipStream_t stream) {
    const float* y     = (const float*)d_in[0];
    const int*   ei    = (const int*)d_in[1];
    const float* ew    = (const float*)d_in[2];
    const int*   batch = (const int*)d_in[3];
    const float* tag_w = (const float*)d_in[4];
    const float* tag_b = (const float*)d_in[5];
    const float* gnw   = (const float*)d_in[6];
    const float* gnb   = (const float*)d_in[7];
    const float* gms   = (const float*)d_in[8];

    const int N = in_sizes[0] / F;
    const int E = in_sizes[1] / 2;
    const size_t NF = (size_t)N * F;
    const int NB = (N + 255) >> 8;           // dst buckets of 256 nodes
    const int NH = NB * PB;                  // histogram entries
    const int chunk = (E + PB - 1) / PB;
    const int fb = (N * 32 + 255) / 256;
    const int gb = (N + 255) / 256;

    // ---- workspace layout (no memset: S1/S2 zeroed in k_prep) ----
    char* p = (char*)d_ws;
    float* S1 = (float*)p;       p += (size_t)GRAPHS * F * 4;
    float* S2 = (float*)p;       p += (size_t)GRAPHS * F * 4;   // contiguous after S1
    int*   gstart = (int*)p;     p += 512;
    float* dinv = (float*)p;     p += (size_t)N * 4;
    int*   offs = (int*)p;       p += (size_t)(N + 4) * 4;
    int*   hist_t = (int*)p;     p += (size_t)NH * 4;
    int*   bbase = (int*)p;      p += 1040;
    uint2* part = (uint2*)p;     p += (size_t)E * 8;
    unsigned* csr = (unsigned*)p; p += (size_t)E * 4;
    unsigned short* Wf = (unsigned short*)p; p += 4 * 128 * 128 * 2;
    unsigned short* hcat = (unsigned short*)p; p += NF * 2 * 4;   // 4 bf16 slices
    unsigned short* outb = (unsigned short*)p; p += NF * 2;        // bf16; OOB-read pad
    p += 4096;

    MArgs ha;
    ha.y = y; ha.ei = ei; ha.ew = ew; ha.batch = batch;
    ha.tw = tag_w; ha.tb = tag_b; ha.gnw = gnw; ha.gnb = gnb; ha.gms = gms;
    ha.res = (float*)d_out;
    ha.S1 = S1; ha.S2 = S2; ha.gstart = gstart; ha.dinv = dinv; ha.offs = offs;
    ha.hist_t = hist_t; ha.bbase = bbase; ha.part = part; ha.csr = csr;
    ha.Wf = Wf; ha.hcat = hcat; ha.outb = outb;
    ha.N = N; ha.E = E; ha.NB = NB; ha.chunk = chunk; ha.fb = fb; ha.gb = gb;
    ha.NF = NF;

    k_prep<<<256 + fb + 256 + gb + 8, 256, 0, stream>>>(ha);
    k_part<<<PB, 256, 0, stream>>>(ha);
    k_bucket<<<NB, 256, 0, stream>>>(ha);
    k_hop<1><<<(N + 3) / 4, 256, 0, stream>>>(ha);
    k_hop<2><<<(N + 3) / 4, 256, 0, stream>>>(ha);
    k_hop<3><<<(N + 3) / 4, 256, 0, stream>>>(ha);
    k_gemm<<<(N + 31) / 32, 256, 0, stream>>>(ha);
    k_final<<<(N * 32 + 255) / 256, 256, 0, stream>>>(ha);
}